// Round 10
// baseline (236.353 us; speedup 1.0000x reference)
//
#include <hip/hip_runtime.h>
#include <hip/hip_bf16.h>

#define N_NODES 50000
#define N_EDGES 400000
#define D 16
#define HID 64

#define SCAN_B 256
#define SCAN_G ((N_NODES + SCAN_B - 1) / SCAN_B)   // 196
#define NB_E2 ((N_EDGES + 511) / 512)              // 782 edge blocks (2 edges/thread)

typedef unsigned short ushort_t;

// ---------------- int-indexed workspace layout (CSR path) ----------------
#define CNT4_OFF  0                       // [4][N] replicated counts (memset to 0)
#define DEG_OFF   (4 * N_NODES)           // [N] total degree
#define OFF_OFF   (5 * N_NODES)           // [N+1] CSR offsets
#define CUR_OFF   (6 * N_NODES + 1)       // [N] claim cursors
#define BS_OFF    (7 * N_NODES + 1)       // [SCAN_G] block sums
#define MSG_OFF_I (((BS_OFF + SCAN_G) + 3) & ~3)
// bf16-input path: msgs = 2E*16 bf16 (2E*8 ints); f32 path: 2E*16 f32
#define CSR_NEEDED_BYTES ((size_t)(MSG_OFF_I + 2 * N_EDGES * D) * 4 + 64)

// ---------------- fallback (atomic) layout ----------------
#define FB_NDEG   (N_NODES)
#define FB_NACC   (N_NODES * D)
#define FB_FLAGS  (FB_NDEG + FB_NACC)

// ---------------------------------------------------------------------------
// dtype helpers
// ---------------------------------------------------------------------------
__device__ __forceinline__ float bf_bits(ushort_t us) {
    return __uint_as_float(((unsigned)us) << 16);
}
__device__ __forceinline__ float lo_bf(unsigned u) { return __uint_as_float(u << 16); }
__device__ __forceinline__ float hi_bf(unsigned u) { return __uint_as_float(u & 0xffff0000u); }
__device__ __forceinline__ ushort_t f2bf(float v) {   // round-to-nearest-even
    unsigned u = __float_as_uint(v);
    unsigned r = (u + 0x7fffu + ((u >> 16) & 1u)) >> 16;
    return (ushort_t)r;
}
__device__ __forceinline__ float ld_f(const void* p, int idx, int f32) {
    return f32 ? ((const float*)p)[idx]
               : bf_bits(((const ushort_t*)p)[idx]);
}

__device__ __forceinline__ void load16(const void* __restrict__ p, long long base,
                                       int f32, float* o) {
    if (f32) {
        const float4* q = (const float4*)((const float*)p + base);
        float4 a = q[0], b = q[1], c = q[2], d = q[3];
        o[0]=a.x; o[1]=a.y; o[2]=a.z; o[3]=a.w;
        o[4]=b.x; o[5]=b.y; o[6]=b.z; o[7]=b.w;
        o[8]=c.x; o[9]=c.y; o[10]=c.z; o[11]=c.w;
        o[12]=d.x; o[13]=d.y; o[14]=d.z; o[15]=d.w;
    } else {
        const uint4* q = (const uint4*)((const ushort_t*)p + base);
        uint4 a = q[0], b = q[1];
        unsigned u[8] = {a.x, a.y, a.z, a.w, b.x, b.y, b.z, b.w};
#pragma unroll
        for (int k = 0; k < 8; k++) {
            o[2 * k]     = lo_bf(u[k]);
            o[2 * k + 1] = hi_bf(u[k]);
        }
    }
}

__device__ __forceinline__ void load_edge(const void* __restrict__ ei, int e, int is64,
                                          int& s, int& d) {
    if (is64) {
        const long long* p = (const long long*)ei;
        s = (int)p[e];
        d = (int)p[N_EDGES + e];
    } else {
        const int* p = (const int*)ei;
        s = p[e];
        d = p[N_EDGES + e];
    }
}

__device__ __forceinline__ void detect_flags(const void* x, const void* ei, int* flags) {
    const ushort_t* h = (const ushort_t*)x;
    int f32 = 0;
    for (int k = 0; k < 256; k++) {
        float v = bf_bits(h[k]);
        if (!(v == v) || fabsf(v) > 1.0e6f) { f32 = 1; break; }
    }
    const long long* p = (const long long*)ei;
    int i64 = 1;
    for (int k = 0; k < 16; k++) {
        long long v = p[k];
        if (v < 0 || v >= N_NODES) { i64 = 0; break; }
    }
    flags[0] = f32;
    flags[1] = i64;
}

__device__ __forceinline__ void stage_weights(
    const void* W1, const void* b1, const void* W2, const void* b2, int f32,
    float* sW1, float* sW2t, float* sb1, float* sb2)
{
    int t = threadIdx.x;
    for (int idx = t; idx < HID * 2 * D; idx += blockDim.x)
        sW1[idx] = ld_f(W1, idx, f32);
    for (int idx = t; idx < HID * D; idx += blockDim.x) {
        int j = idx / D, i = idx % D;
        sW2t[idx] = ld_f(W2, i * HID + j, f32);
    }
    if (t < HID) sb1[t] = ld_f(b1, t, f32);
    if (t < D)  sb2[t] = ld_f(b2, t, f32);
}

// ---------------------------------------------------------------------------
// Full-MLP per-edge math (fallback path)
// ---------------------------------------------------------------------------
__device__ __forceinline__ void edge_math_v4(
    const float* __restrict__ sW1, const float* __restrict__ sW2t,
    const float* __restrict__ sb1, const float* __restrict__ sb2,
    const float* xs, const float* xd, float coef,
    float* ms, float* md)
{
    float vs[D], vd[D];
#pragma unroll
    for (int i = 0; i < D; i++) { vs[i] = sb2[i]; vd[i] = sb2[i]; }
#pragma unroll 4
    for (int j = 0; j < HID; j++) {
        float hs = sb1[j], hd = sb1[j];
        const float4* w4 = (const float4*)&sW1[j * 2 * D];
#pragma unroll
        for (int t = 0; t < 4; t++) {
            float4 wv = w4[t];
            int k = 4 * t;
            hs = fmaf(wv.x, xs[k],     hs); hd = fmaf(wv.x, xd[k],     hd);
            hs = fmaf(wv.y, xs[k + 1], hs); hd = fmaf(wv.y, xd[k + 1], hd);
            hs = fmaf(wv.z, xs[k + 2], hs); hd = fmaf(wv.z, xd[k + 2], hd);
            hs = fmaf(wv.w, xs[k + 3], hs); hd = fmaf(wv.w, xd[k + 3], hd);
        }
#pragma unroll
        for (int t = 0; t < 4; t++) {
            float4 wv = w4[4 + t];
            int k = 4 * t;
            hs = fmaf(wv.x, xd[k],     hs); hd = fmaf(wv.x, xs[k],     hd);
            hs = fmaf(wv.y, xd[k + 1], hs); hd = fmaf(wv.y, xs[k + 1], hd);
            hs = fmaf(wv.z, xd[k + 2], hs); hd = fmaf(wv.z, xs[k + 2], hd);
            hs = fmaf(wv.w, xd[k + 3], hs); hd = fmaf(wv.w, xs[k + 3], hd);
        }
        hs = fmaxf(hs, 0.0f);
        hd = fmaxf(hd, 0.0f);
        const float4* w24 = (const float4*)&sW2t[j * D];
#pragma unroll
        for (int t = 0; t < 4; t++) {
            float4 u = w24[t];
            int i = 4 * t;
            vs[i]     = fmaf(u.x, hs, vs[i]);     vd[i]     = fmaf(u.x, hd, vd[i]);
            vs[i + 1] = fmaf(u.y, hs, vs[i + 1]); vd[i + 1] = fmaf(u.y, hd, vd[i + 1]);
            vs[i + 2] = fmaf(u.z, hs, vs[i + 2]); vd[i + 2] = fmaf(u.z, hd, vd[i + 2]);
            vs[i + 3] = fmaf(u.w, hs, vs[i + 3]); vd[i + 3] = fmaf(u.w, hd, vd[i + 3]);
        }
    }
    float ns = 0.0f, nd = 0.0f;
#pragma unroll
    for (int i = 0; i < D; i++) { ns = fmaf(vs[i], vs[i], ns); nd = fmaf(vd[i], vd[i], nd); }
    float is_ = 1.0f / fmaxf(sqrtf(ns), 1e-12f);
    float id_ = 1.0f / fmaxf(sqrtf(nd), 1e-12f);
#pragma unroll
    for (int i = 0; i < D; i++) { vs[i] *= is_; vd[i] *= id_; }
    float dot1 = 0.0f;
#pragma unroll
    for (int i = 0; i < D; i++) dot1 = fmaf(vd[i], xd[i], dot1);
#pragma unroll
    for (int i = 0; i < D; i++) ms[i] = fmaf(-2.0f * dot1, vd[i], xd[i]);
    float dot2 = 0.0f;
#pragma unroll
    for (int i = 0; i < D; i++) dot2 = fmaf(vs[i], ms[i], dot2);
#pragma unroll
    for (int i = 0; i < D; i++) ms[i] = coef * fmaf(-2.0f * dot2, vs[i], ms[i]);
    float dot3 = 0.0f;
#pragma unroll
    for (int i = 0; i < D; i++) dot3 = fmaf(vs[i], xs[i], dot3);
#pragma unroll
    for (int i = 0; i < D; i++) md[i] = fmaf(-2.0f * dot3, vs[i], xs[i]);
    float dot4 = 0.0f;
#pragma unroll
    for (int i = 0; i < D; i++) dot4 = fmaf(vd[i], md[i], dot4);
#pragma unroll
    for (int i = 0; i < D; i++) md[i] = coef * fmaf(-2.0f * dot4, vd[i], md[i]);
}

// ===========================================================================
// CSR path kernels
// ===========================================================================
__global__ void csr_count_kernel(const void* __restrict__ ei,
                                 const void* __restrict__ x,
                                 int* __restrict__ wsI) {
    __shared__ int sfl[2];
    if (threadIdx.x == 0) detect_flags(x, ei, sfl);
    __syncthreads();
    int i64 = sfl[1];
    int e = blockIdx.x * blockDim.x + threadIdx.x;
    if (e >= N_EDGES) return;
    int s, d;
    load_edge(ei, e, i64, s, d);
    int r = (e & 3) * N_NODES;
    atomicAdd(&wsI[CNT4_OFF + r + s], 1);
    atomicAdd(&wsI[CNT4_OFF + r + d], 1);
}

// scan1: fold replicas -> DEG, per-block sums -> BS
__global__ __launch_bounds__(SCAN_B) void csr_scan1_kernel(int* __restrict__ wsI) {
    __shared__ int sm[SCAN_B];
    int t = threadIdx.x;
    int g = blockIdx.x * SCAN_B + t;
    int c = 0;
    if (g < N_NODES) {
        c = wsI[CNT4_OFF + g] + wsI[CNT4_OFF + N_NODES + g]
          + wsI[CNT4_OFF + 2 * N_NODES + g] + wsI[CNT4_OFF + 3 * N_NODES + g];
        wsI[DEG_OFF + g] = c;
    }
    sm[t] = c;
    __syncthreads();
    for (int st = SCAN_B / 2; st > 0; st >>= 1) {
        if (t < st) sm[t] += sm[t + st];
        __syncthreads();
    }
    if (t == 0) wsI[BS_OFF + blockIdx.x] = sm[0];
}

// scan3: every block scans BS locally, then its own chunk.
__global__ __launch_bounds__(SCAN_B) void csr_scan3_kernel(int* __restrict__ wsI) {
    __shared__ int sB[SCAN_B];
    __shared__ int sm[SCAN_B];
    int t = threadIdx.x;
    int bsv = (t < SCAN_G) ? wsI[BS_OFF + t] : 0;
    sB[t] = bsv;
    __syncthreads();
    for (int st = 1; st < SCAN_B; st <<= 1) {
        int u = (t >= st) ? sB[t - st] : 0;
        __syncthreads();
        sB[t] += u;
        __syncthreads();
    }
    int blockBase = sB[blockIdx.x] - wsI[BS_OFF + blockIdx.x];

    int g = blockIdx.x * SCAN_B + t;
    int c = (g < N_NODES) ? wsI[DEG_OFF + g] : 0;
    sm[t] = c;
    __syncthreads();
    for (int st = 1; st < SCAN_B; st <<= 1) {
        int u = (t >= st) ? sm[t - st] : 0;
        __syncthreads();
        sm[t] += u;
        __syncthreads();
    }
    int excl = sm[t] - c + blockBase;
    if (g < N_NODES) {
        wsI[OFF_OFF + g] = excl;
        wsI[CUR_OFF + g] = excl;
        if (g == N_NODES - 1) wsI[OFF_OFF + N_NODES] = excl + c;
    }
}

// ---------------------------------------------------------------------------
// Message epilogue for one edge (vs/vd raw accumulators; xs/xd in registers).
// Claims slots LATE (early atomics block the vmcnt FIFO behind them — R8).
// ---------------------------------------------------------------------------
__device__ __forceinline__ void edge_epilogue(
    float* vs, float* vd, const float* xs, const float* xd,
    int s, int d, float coef, int active, int f32, int* __restrict__ wsI)
{
    float ns = 0.0f, nd = 0.0f;
#pragma unroll
    for (int i = 0; i < D; i++) { ns = fmaf(vs[i], vs[i], ns); nd = fmaf(vd[i], vd[i], nd); }
    float is_ = 1.0f / fmaxf(sqrtf(ns), 1e-12f);
    float id_ = 1.0f / fmaxf(sqrtf(nd), 1e-12f);
#pragma unroll
    for (int i = 0; i < D; i++) { vs[i] *= is_; vd[i] *= id_; }

    float ms[D], md[D];
    float dot1 = 0.0f;
#pragma unroll
    for (int i = 0; i < D; i++) dot1 = fmaf(vd[i], xd[i], dot1);
#pragma unroll
    for (int i = 0; i < D; i++) ms[i] = fmaf(-2.0f * dot1, vd[i], xd[i]);
    float dot2 = 0.0f;
#pragma unroll
    for (int i = 0; i < D; i++) dot2 = fmaf(vs[i], ms[i], dot2);
#pragma unroll
    for (int i = 0; i < D; i++) ms[i] = coef * fmaf(-2.0f * dot2, vs[i], ms[i]);
    float dot3 = 0.0f;
#pragma unroll
    for (int i = 0; i < D; i++) dot3 = fmaf(vs[i], xs[i], dot3);
#pragma unroll
    for (int i = 0; i < D; i++) md[i] = fmaf(-2.0f * dot3, vs[i], xs[i]);
    float dot4 = 0.0f;
#pragma unroll
    for (int i = 0; i < D; i++) dot4 = fmaf(vd[i], md[i], dot4);
#pragma unroll
    for (int i = 0; i < D; i++) md[i] = coef * fmaf(-2.0f * dot4, vd[i], md[i]);

    if (!active) return;
    if (f32) {
        float* msg = (float*)(wsI + MSG_OFF_I);
        int slot_s = atomicAdd(&wsI[CUR_OFF + s], 1);
        float4* m0 = (float4*)(msg + (long long)slot_s * D);
        m0[0] = make_float4(ms[0], ms[1], ms[2], ms[3]);
        m0[1] = make_float4(ms[4], ms[5], ms[6], ms[7]);
        m0[2] = make_float4(ms[8], ms[9], ms[10], ms[11]);
        m0[3] = make_float4(ms[12], ms[13], ms[14], ms[15]);
        int slot_d = atomicAdd(&wsI[CUR_OFF + d], 1);
        float4* m1 = (float4*)(msg + (long long)slot_d * D);
        m1[0] = make_float4(md[0], md[1], md[2], md[3]);
        m1[1] = make_float4(md[4], md[5], md[6], md[7]);
        m1[2] = make_float4(md[8], md[9], md[10], md[11]);
        m1[3] = make_float4(md[12], md[13], md[14], md[15]);
    } else {
        ushort_t* msgh = (ushort_t*)(wsI + MSG_OFF_I);
        unsigned pk[8];
#pragma unroll
        for (int i = 0; i < D; i += 2)
            pk[i >> 1] = (unsigned)f2bf(ms[i]) | ((unsigned)f2bf(ms[i + 1]) << 16);
        int slot_s = atomicAdd(&wsI[CUR_OFF + s], 1);
        uint4* mp = (uint4*)(msgh + (long long)slot_s * D);
        mp[0] = make_uint4(pk[0], pk[1], pk[2], pk[3]);
        mp[1] = make_uint4(pk[4], pk[5], pk[6], pk[7]);
#pragma unroll
        for (int i = 0; i < D; i += 2)
            pk[i >> 1] = (unsigned)f2bf(md[i]) | ((unsigned)f2bf(md[i + 1]) << 16);
        int slot_d = atomicAdd(&wsI[CUR_OFF + d], 1);
        uint4* mq = (uint4*)(msgh + (long long)slot_d * D);
        mq[0] = make_uint4(pk[0], pk[1], pk[2], pk[3]);
        mq[1] = make_uint4(pk[4], pk[5], pk[6], pk[7]);
    }
}

// ---------------------------------------------------------------------------
// Edge kernel: 2 edges per thread. Each broadcast weight row feeds 4 h-chains
// (192 FMA / 12 ds_read_b128 per j) — ILP hides LDS latency that limited R7
// (VALUBusy 66% @ 2.5 waves/SIMD). __launch_bounds__(256,2) grants up to 256
// VGPRs for the ~150-reg live set.
// ---------------------------------------------------------------------------
__global__ __launch_bounds__(256, 2) void csr_edge2_kernel(
    const void* __restrict__ x,
    const void* __restrict__ ei,
    const void* __restrict__ W1,
    const void* __restrict__ b1,
    const void* __restrict__ W2,
    const void* __restrict__ b2,
    int* __restrict__ wsI)
{
    __shared__ __align__(16) float sW1[HID * 2 * D];
    __shared__ __align__(16) float sW2t[HID * D];
    __shared__ float sb1[HID];
    __shared__ float sb2[D];
    __shared__ int sfl[2];

    if (threadIdx.x == 0) detect_flags(x, ei, sfl);
    __syncthreads();
    int f32 = sfl[0], i64 = sfl[1];
    stage_weights(W1, b1, W2, b2, f32, sW1, sW2t, sb1, sb2);
    __syncthreads();

    int t = threadIdx.x;
    int e0 = blockIdx.x * 512 + t;
    int e1 = e0 + 256;
    int act0 = e0 < N_EDGES;
    int act1 = e1 < N_EDGES;
    int c0 = act0 ? e0 : 0;
    int c1 = act1 ? e1 : 0;

    int s0, d0, s1, d1;
    load_edge(ei, c0, i64, s0, d0);
    load_edge(ei, c1, i64, s1, d1);

    float degs0 = (float)wsI[DEG_OFF + s0];
    float degd0 = (float)wsI[DEG_OFF + d0];
    float degs1 = (float)wsI[DEG_OFF + s1];
    float degd1 = (float)wsI[DEG_OFF + d1];
    float coef0 = (1.0f / sqrtf(fmaxf(degs0, 1e-5f))) * (1.0f / sqrtf(fmaxf(degd0, 1e-5f)));
    float coef1 = (1.0f / sqrtf(fmaxf(degs1, 1e-5f))) * (1.0f / sqrtf(fmaxf(degd1, 1e-5f)));

    float xs0[D], xd0[D], xs1[D], xd1[D];
    load16(x, (long long)s0 * D, f32, xs0);
    load16(x, (long long)d0 * D, f32, xd0);
    load16(x, (long long)s1 * D, f32, xs1);
    load16(x, (long long)d1 * D, f32, xd1);

    float vs0[D], vd0[D], vs1[D], vd1[D];
#pragma unroll
    for (int i = 0; i < D; i++) {
        float b = sb2[i];
        vs0[i] = b; vd0[i] = b; vs1[i] = b; vd1[i] = b;
    }

#pragma unroll 2
    for (int j = 0; j < HID; j++) {
        float bj = sb1[j];
        float hs0 = bj, hd0 = bj, hs1 = bj, hd1 = bj;
        const float4* w4 = (const float4*)&sW1[j * 2 * D];
#pragma unroll
        for (int tt = 0; tt < 4; tt++) {
            float4 wv = w4[tt];
            int k = 4 * tt;
            hs0 = fmaf(wv.x, xs0[k],     hs0); hd0 = fmaf(wv.x, xd0[k],     hd0);
            hs1 = fmaf(wv.x, xs1[k],     hs1); hd1 = fmaf(wv.x, xd1[k],     hd1);
            hs0 = fmaf(wv.y, xs0[k + 1], hs0); hd0 = fmaf(wv.y, xd0[k + 1], hd0);
            hs1 = fmaf(wv.y, xs1[k + 1], hs1); hd1 = fmaf(wv.y, xd1[k + 1], hd1);
            hs0 = fmaf(wv.z, xs0[k + 2], hs0); hd0 = fmaf(wv.z, xd0[k + 2], hd0);
            hs1 = fmaf(wv.z, xs1[k + 2], hs1); hd1 = fmaf(wv.z, xd1[k + 2], hd1);
            hs0 = fmaf(wv.w, xs0[k + 3], hs0); hd0 = fmaf(wv.w, xd0[k + 3], hd0);
            hs1 = fmaf(wv.w, xs1[k + 3], hs1); hd1 = fmaf(wv.w, xd1[k + 3], hd1);
        }
#pragma unroll
        for (int tt = 0; tt < 4; tt++) {
            float4 wv = w4[4 + tt];
            int k = 4 * tt;
            hs0 = fmaf(wv.x, xd0[k],     hs0); hd0 = fmaf(wv.x, xs0[k],     hd0);
            hs1 = fmaf(wv.x, xd1[k],     hs1); hd1 = fmaf(wv.x, xs1[k],     hd1);
            hs0 = fmaf(wv.y, xd0[k + 1], hs0); hd0 = fmaf(wv.y, xs0[k + 1], hd0);
            hs1 = fmaf(wv.y, xd1[k + 1], hs1); hd1 = fmaf(wv.y, xs1[k + 1], hd1);
            hs0 = fmaf(wv.z, xd0[k + 2], hs0); hd0 = fmaf(wv.z, xs0[k + 2], hd0);
            hs1 = fmaf(wv.z, xd1[k + 2], hs1); hd1 = fmaf(wv.z, xs1[k + 2], hd1);
            hs0 = fmaf(wv.w, xd0[k + 3], hs0); hd0 = fmaf(wv.w, xs0[k + 3], hd0);
            hs1 = fmaf(wv.w, xd1[k + 3], hs1); hd1 = fmaf(wv.w, xs1[k + 3], hd1);
        }
        hs0 = fmaxf(hs0, 0.0f); hd0 = fmaxf(hd0, 0.0f);
        hs1 = fmaxf(hs1, 0.0f); hd1 = fmaxf(hd1, 0.0f);
        const float4* w24 = (const float4*)&sW2t[j * D];
#pragma unroll
        for (int tt = 0; tt < 4; tt++) {
            float4 u = w24[tt];
            int i = 4 * tt;
            vs0[i]     = fmaf(u.x, hs0, vs0[i]);     vd0[i]     = fmaf(u.x, hd0, vd0[i]);
            vs1[i]     = fmaf(u.x, hs1, vs1[i]);     vd1[i]     = fmaf(u.x, hd1, vd1[i]);
            vs0[i + 1] = fmaf(u.y, hs0, vs0[i + 1]); vd0[i + 1] = fmaf(u.y, hd0, vd0[i + 1]);
            vs1[i + 1] = fmaf(u.y, hs1, vs1[i + 1]); vd1[i + 1] = fmaf(u.y, hd1, vd1[i + 1]);
            vs0[i + 2] = fmaf(u.z, hs0, vs0[i + 2]); vd0[i + 2] = fmaf(u.z, hd0, vd0[i + 2]);
            vs1[i + 2] = fmaf(u.z, hs1, vs1[i + 2]); vd1[i + 2] = fmaf(u.z, hd1, vd1[i + 2]);
            vs0[i + 3] = fmaf(u.w, hs0, vs0[i + 3]); vd0[i + 3] = fmaf(u.w, hd0, vd0[i + 3]);
            vs1[i + 3] = fmaf(u.w, hs1, vs1[i + 3]); vd1[i + 3] = fmaf(u.w, hd1, vd1[i + 3]);
        }
    }

    edge_epilogue(vs0, vd0, xs0, xd0, s0, d0, coef0, act0, f32, wsI);
    edge_epilogue(vs1, vd1, xs1, xd1, s1, d1, coef1, act1, f32, wsI);
}

// Gather: 4 lanes per node (lane c -> dims 4c..4c+3), unroll-2 accumulation.
__global__ __launch_bounds__(256) void csr_gather_kernel(
    const void* __restrict__ x,
    const void* __restrict__ ei,
    const int* __restrict__ wsI,
    void* __restrict__ out)
{
    __shared__ int sfl[2];
    if (threadIdx.x == 0) detect_flags(x, ei, sfl);
    __syncthreads();
    int f32 = sfl[0];

    int n = blockIdx.x * 64 + (threadIdx.x >> 2);
    int c = threadIdx.x & 3;
    if (n >= N_NODES) return;

    const int* off = wsI + OFF_OFF;
    int beg = off[n], end = off[n + 1];

    float4 a = make_float4(0.0f, 0.0f, 0.0f, 0.0f);
    if (f32) {
        const float4* msg4 = (const float4*)(wsI + MSG_OFF_I);
        int it = beg;
        for (; it + 2 <= end; it += 2) {
            float4 u = msg4[(long long)it * 4 + c];
            float4 v = msg4[(long long)(it + 1) * 4 + c];
            a.x += u.x + v.x; a.y += u.y + v.y; a.z += u.z + v.z; a.w += u.w + v.w;
        }
        if (it < end) {
            float4 u = msg4[(long long)it * 4 + c];
            a.x += u.x; a.y += u.y; a.z += u.z; a.w += u.w;
        }
    } else {
        const ushort_t* msgh = (const ushort_t*)(wsI + MSG_OFF_I);
        int it = beg;
        for (; it + 2 <= end; it += 2) {
            uint2 u = *(const uint2*)(msgh + (long long)it * D + 4 * c);
            uint2 v = *(const uint2*)(msgh + (long long)(it + 1) * D + 4 * c);
            a.x += lo_bf(u.x) + lo_bf(v.x);
            a.y += hi_bf(u.x) + hi_bf(v.x);
            a.z += lo_bf(u.y) + lo_bf(v.y);
            a.w += hi_bf(u.y) + hi_bf(v.y);
        }
        if (it < end) {
            uint2 u = *(const uint2*)(msgh + (long long)it * D + 4 * c);
            a.x += lo_bf(u.x); a.y += hi_bf(u.x);
            a.z += lo_bf(u.y); a.w += hi_bf(u.y);
        }
    }

    long long xb = (long long)n * D + 4 * c;
    float4 xv;
    if (f32) {
        xv = *(const float4*)((const float*)x + xb);
    } else {
        uint2 u = *(const uint2*)((const ushort_t*)x + xb);
        xv.x = lo_bf(u.x); xv.y = hi_bf(u.x);
        xv.z = lo_bf(u.y); xv.w = hi_bf(u.y);
    }
    float4 r;
    r.x = fmaxf(xv.x + a.x, 0.0f);
    r.y = fmaxf(xv.y + a.y, 0.0f);
    r.z = fmaxf(xv.z + a.z, 0.0f);
    r.w = fmaxf(xv.w + a.w, 0.0f);
    if (f32) {
        *(float4*)((float*)out + xb) = r;
    } else {
        uint2 o;
        o.x = (unsigned)f2bf(r.x) | ((unsigned)f2bf(r.y) << 16);
        o.y = (unsigned)f2bf(r.z) | ((unsigned)f2bf(r.w) << 16);
        *(uint2*)((ushort_t*)out + xb) = o;
    }
}

// ===========================================================================
// Fallback path (known-good): float atomics into acc
// ===========================================================================
__global__ void fb_init_kernel(float* __restrict__ ws,
                               const void* __restrict__ x,
                               const void* __restrict__ ei) {
    int i = blockIdx.x * blockDim.x + threadIdx.x;
    if (i < FB_FLAGS) ws[i] = 0.0f;
    if (blockIdx.x == 0 && threadIdx.x == 0)
        detect_flags(x, ei, (int*)(ws + FB_FLAGS));
}

__global__ void fb_deg_kernel(const void* __restrict__ ei, float* __restrict__ ws) {
    int i64 = ((const int*)(ws + FB_FLAGS))[1];
    int e = blockIdx.x * blockDim.x + threadIdx.x;
    if (e >= N_EDGES) return;
    int s, d;
    load_edge(ei, e, i64, s, d);
    atomicAdd(&ws[s], 1.0f);
    atomicAdd(&ws[d], 1.0f);
}

__global__ __launch_bounds__(256) void fb_edge_kernel(
    const void* __restrict__ x, const void* __restrict__ ei,
    const void* __restrict__ W1, const void* __restrict__ b1,
    const void* __restrict__ W2, const void* __restrict__ b2,
    float* __restrict__ ws)
{
    __shared__ __align__(16) float sW1[HID * 2 * D];
    __shared__ __align__(16) float sW2t[HID * D];
    __shared__ float sb1[HID];
    __shared__ float sb2[D];
    const int* flags = (const int*)(ws + FB_FLAGS);
    int f32 = flags[0], i64 = flags[1];
    stage_weights(W1, b1, W2, b2, f32, sW1, sW2t, sb1, sb2);
    __syncthreads();
    int e = blockIdx.x * blockDim.x + threadIdx.x;
    if (e >= N_EDGES) return;
    int s, d;
    load_edge(ei, e, i64, s, d);
    float xs[D], xd[D];
    load16(x, (long long)s * D, f32, xs);
    load16(x, (long long)d * D, f32, xd);
    float coef = (1.0f / sqrtf(fmaxf(ws[s], 1e-5f))) * (1.0f / sqrtf(fmaxf(ws[d], 1e-5f)));
    float ms[D], md[D];
    edge_math_v4(sW1, sW2t, sb1, sb2, xs, xd, coef, ms, md);
    float* acc = ws + FB_NDEG;
#pragma unroll
    for (int i = 0; i < D; i++) atomicAdd(&acc[(long long)s * D + i], ms[i]);
#pragma unroll
    for (int i = 0; i < D; i++) atomicAdd(&acc[(long long)d * D + i], md[i]);
}

__global__ void fb_finalize_kernel(const void* __restrict__ x,
                                   const float* __restrict__ ws,
                                   void* __restrict__ out)
{
    int f32 = ((const int*)(ws + FB_FLAGS))[0];
    const float* acc = ws + FB_NDEG;
    int i = blockIdx.x * blockDim.x + threadIdx.x;
    if (i >= FB_NACC) return;
    float v = ld_f(x, i, f32) + acc[i];
    v = fmaxf(v, 0.0f);
    if (f32) ((float*)out)[i] = v;
    else     ((__hip_bfloat16*)out)[i] = __float2bfloat16(v);
}

// ===========================================================================
extern "C" void kernel_launch(void* const* d_in, const int* in_sizes, int n_in,
                              void* d_out, int out_size, void* d_ws, size_t ws_size,
                              hipStream_t stream)
{
    const void* x  = d_in[0];
    const void* ei = d_in[1];
    const void* W1 = d_in[2];
    const void* b1 = d_in[3];
    const void* W2 = d_in[4];
    const void* b2 = d_in[5];

    int blk = 256;
    if (ws_size >= CSR_NEEDED_BYTES) {
        int* wsI = (int*)d_ws;
        hipMemsetAsync(d_ws, 0, (size_t)4 * N_NODES * sizeof(int), stream);
        csr_count_kernel<<<(N_EDGES + blk - 1) / blk, blk, 0, stream>>>(ei, x, wsI);
        csr_scan1_kernel<<<SCAN_G, SCAN_B, 0, stream>>>(wsI);
        csr_scan3_kernel<<<SCAN_G, SCAN_B, 0, stream>>>(wsI);
        csr_edge2_kernel<<<NB_E2, blk, 0, stream>>>(x, ei, W1, b1, W2, b2, wsI);
        csr_gather_kernel<<<(N_NODES + 63) / 64, blk, 0, stream>>>(x, ei, wsI, d_out);
    } else {
        float* ws = (float*)d_ws;
        fb_init_kernel<<<(FB_FLAGS + blk - 1) / blk, blk, 0, stream>>>(ws, x, ei);
        fb_deg_kernel<<<(N_EDGES + blk - 1) / blk, blk, 0, stream>>>(ei, ws);
        fb_edge_kernel<<<(N_EDGES + blk - 1) / blk, blk, 0, stream>>>(x, ei, W1, b1, W2, b2, ws);
        fb_finalize_kernel<<<(FB_NACC + blk - 1) / blk, blk, 0, stream>>>(x, ws, d_out);
    }
}

// Round 11
// 206.261 us; speedup vs baseline: 1.1459x; 1.1459x over previous
//
#include <hip/hip_runtime.h>
#include <hip/hip_bf16.h>

#define N_NODES 50000
#define N_EDGES 400000
#define D 16
#define HID 64

#define SCAN_B 256
#define SCAN_G ((N_NODES + SCAN_B - 1) / SCAN_B)   // 196

typedef unsigned short ushort_t;
typedef __attribute__((ext_vector_type(2))) float f32x2;

// ---------------- int-indexed workspace layout (CSR path) ----------------
#define CNT4_OFF  0                       // [4][N] replicated counts (memset to 0)
#define DEG_OFF   (4 * N_NODES)           // [N] total degree
#define OFF_OFF   (5 * N_NODES)           // [N+1] CSR offsets
#define CUR_OFF   (6 * N_NODES + 1)       // [N] claim cursors
#define BS_OFF    (7 * N_NODES + 1)       // [SCAN_G] block sums
#define MSG_OFF_I (((BS_OFF + SCAN_G) + 3) & ~3)  // [2E*16] fp32 msgs
#define CSR_NEEDED_BYTES ((size_t)(MSG_OFF_I + 2 * N_EDGES * D) * 4 + 64)

// ---------------- fallback (atomic) layout ----------------
#define FB_NDEG   (N_NODES)
#define FB_NACC   (N_NODES * D)
#define FB_FLAGS  (FB_NDEG + FB_NACC)

// ---------------------------------------------------------------------------
// dtype helpers
// ---------------------------------------------------------------------------
__device__ __forceinline__ float bf_bits(ushort_t us) {
    return __uint_as_float(((unsigned)us) << 16);
}
__device__ __forceinline__ float lo_bf(unsigned u) { return __uint_as_float(u << 16); }
__device__ __forceinline__ float hi_bf(unsigned u) { return __uint_as_float(u & 0xffff0000u); }
__device__ __forceinline__ ushort_t f2bf(float v) {
    unsigned u = __float_as_uint(v);
    unsigned r = (u + 0x7fffu + ((u >> 16) & 1u)) >> 16;
    return (ushort_t)r;
}
__device__ __forceinline__ float ld_f(const void* p, int idx, int f32) {
    return f32 ? ((const float*)p)[idx]
               : bf_bits(((const ushort_t*)p)[idx]);
}

__device__ __forceinline__ f32x2 pk_fma(f32x2 a, f32x2 b, f32x2 c) {
#if __has_builtin(__builtin_elementwise_fma)
    return __builtin_elementwise_fma(a, b, c);   // -> v_pk_fma_f32 on gfx950
#else
    f32x2 r;
    r.x = fmaf(a.x, b.x, c.x);
    r.y = fmaf(a.y, b.y, c.y);
    return r;
#endif
}

// load 16 values as 8 f32x2 pairs
__device__ __forceinline__ void load16_p(const void* __restrict__ p, long long base,
                                         int f32, f32x2* o) {
    if (f32) {
        const float4* q = (const float4*)((const float*)p + base);
#pragma unroll
        for (int t = 0; t < 4; t++) {
            float4 v = q[t];
            o[2 * t]     = (f32x2){v.x, v.y};
            o[2 * t + 1] = (f32x2){v.z, v.w};
        }
    } else {
        const uint4* q = (const uint4*)((const ushort_t*)p + base);
        uint4 a = q[0], b = q[1];
        unsigned u[8] = {a.x, a.y, a.z, a.w, b.x, b.y, b.z, b.w};
#pragma unroll
        for (int k = 0; k < 8; k++)
            o[k] = (f32x2){lo_bf(u[k]), hi_bf(u[k])};
    }
}

__device__ __forceinline__ void load16(const void* __restrict__ p, long long base,
                                       int f32, float* o) {
    if (f32) {
        const float4* q = (const float4*)((const float*)p + base);
        float4 a = q[0], b = q[1], c = q[2], d = q[3];
        o[0]=a.x; o[1]=a.y; o[2]=a.z; o[3]=a.w;
        o[4]=b.x; o[5]=b.y; o[6]=b.z; o[7]=b.w;
        o[8]=c.x; o[9]=c.y; o[10]=c.z; o[11]=c.w;
        o[12]=d.x; o[13]=d.y; o[14]=d.z; o[15]=d.w;
    } else {
        const uint4* q = (const uint4*)((const ushort_t*)p + base);
        uint4 a = q[0], b = q[1];
        unsigned u[8] = {a.x, a.y, a.z, a.w, b.x, b.y, b.z, b.w};
#pragma unroll
        for (int k = 0; k < 8; k++) {
            o[2 * k]     = lo_bf(u[k]);
            o[2 * k + 1] = hi_bf(u[k]);
        }
    }
}

__device__ __forceinline__ void load_edge(const void* __restrict__ ei, int e, int is64,
                                          int& s, int& d) {
    if (is64) {
        const long long* p = (const long long*)ei;
        s = (int)p[e];
        d = (int)p[N_EDGES + e];
    } else {
        const int* p = (const int*)ei;
        s = p[e];
        d = p[N_EDGES + e];
    }
}

__device__ __forceinline__ void detect_flags(const void* x, const void* ei, int* flags) {
    const ushort_t* h = (const ushort_t*)x;
    int f32 = 0;
    for (int k = 0; k < 256; k++) {
        float v = bf_bits(h[k]);
        if (!(v == v) || fabsf(v) > 1.0e6f) { f32 = 1; break; }
    }
    const long long* p = (const long long*)ei;
    int i64 = 1;
    for (int k = 0; k < 16; k++) {
        long long v = p[k];
        if (v < 0 || v >= N_NODES) { i64 = 0; break; }
    }
    flags[0] = f32;
    flags[1] = i64;
}

__device__ __forceinline__ void stage_weights(
    const void* W1, const void* b1, const void* W2, const void* b2, int f32,
    float* sW1, float* sW2t, float* sb1, float* sb2)
{
    int t = threadIdx.x;
    for (int idx = t; idx < HID * 2 * D; idx += blockDim.x)
        sW1[idx] = ld_f(W1, idx, f32);
    for (int idx = t; idx < HID * D; idx += blockDim.x) {
        int j = idx / D, i = idx % D;
        sW2t[idx] = ld_f(W2, i * HID + j, f32);
    }
    if (t < HID) sb1[t] = ld_f(b1, t, f32);
    if (t < D)  sb2[t] = ld_f(b2, t, f32);
}

// ---------------------------------------------------------------------------
// Full-MLP per-edge math (fallback path, scalar — known-good)
// ---------------------------------------------------------------------------
__device__ __forceinline__ void edge_math_v4(
    const float* __restrict__ sW1, const float* __restrict__ sW2t,
    const float* __restrict__ sb1, const float* __restrict__ sb2,
    const float* xs, const float* xd, float coef,
    float* ms, float* md)
{
    float vs[D], vd[D];
#pragma unroll
    for (int i = 0; i < D; i++) { vs[i] = sb2[i]; vd[i] = sb2[i]; }
#pragma unroll 4
    for (int j = 0; j < HID; j++) {
        float hs = sb1[j], hd = sb1[j];
        const float4* w4 = (const float4*)&sW1[j * 2 * D];
#pragma unroll
        for (int t = 0; t < 4; t++) {
            float4 wv = w4[t];
            int k = 4 * t;
            hs = fmaf(wv.x, xs[k],     hs); hd = fmaf(wv.x, xd[k],     hd);
            hs = fmaf(wv.y, xs[k + 1], hs); hd = fmaf(wv.y, xd[k + 1], hd);
            hs = fmaf(wv.z, xs[k + 2], hs); hd = fmaf(wv.z, xd[k + 2], hd);
            hs = fmaf(wv.w, xs[k + 3], hs); hd = fmaf(wv.w, xd[k + 3], hd);
        }
#pragma unroll
        for (int t = 0; t < 4; t++) {
            float4 wv = w4[4 + t];
            int k = 4 * t;
            hs = fmaf(wv.x, xd[k],     hs); hd = fmaf(wv.x, xs[k],     hd);
            hs = fmaf(wv.y, xd[k + 1], hs); hd = fmaf(wv.y, xs[k + 1], hd);
            hs = fmaf(wv.z, xd[k + 2], hs); hd = fmaf(wv.z, xs[k + 2], hd);
            hs = fmaf(wv.w, xd[k + 3], hs); hd = fmaf(wv.w, xs[k + 3], hd);
        }
        hs = fmaxf(hs, 0.0f);
        hd = fmaxf(hd, 0.0f);
        const float4* w24 = (const float4*)&sW2t[j * D];
#pragma unroll
        for (int t = 0; t < 4; t++) {
            float4 u = w24[t];
            int i = 4 * t;
            vs[i]     = fmaf(u.x, hs, vs[i]);     vd[i]     = fmaf(u.x, hd, vd[i]);
            vs[i + 1] = fmaf(u.y, hs, vs[i + 1]); vd[i + 1] = fmaf(u.y, hd, vd[i + 1]);
            vs[i + 2] = fmaf(u.z, hs, vs[i + 2]); vd[i + 2] = fmaf(u.z, hd, vd[i + 2]);
            vs[i + 3] = fmaf(u.w, hs, vs[i + 3]); vd[i + 3] = fmaf(u.w, hd, vd[i + 3]);
        }
    }
    float ns = 0.0f, nd = 0.0f;
#pragma unroll
    for (int i = 0; i < D; i++) { ns = fmaf(vs[i], vs[i], ns); nd = fmaf(vd[i], vd[i], nd); }
    float is_ = 1.0f / fmaxf(sqrtf(ns), 1e-12f);
    float id_ = 1.0f / fmaxf(sqrtf(nd), 1e-12f);
#pragma unroll
    for (int i = 0; i < D; i++) { vs[i] *= is_; vd[i] *= id_; }
    float dot1 = 0.0f;
#pragma unroll
    for (int i = 0; i < D; i++) dot1 = fmaf(vd[i], xd[i], dot1);
#pragma unroll
    for (int i = 0; i < D; i++) ms[i] = fmaf(-2.0f * dot1, vd[i], xd[i]);
    float dot2 = 0.0f;
#pragma unroll
    for (int i = 0; i < D; i++) dot2 = fmaf(vs[i], ms[i], dot2);
#pragma unroll
    for (int i = 0; i < D; i++) ms[i] = coef * fmaf(-2.0f * dot2, vs[i], ms[i]);
    float dot3 = 0.0f;
#pragma unroll
    for (int i = 0; i < D; i++) dot3 = fmaf(vs[i], xs[i], dot3);
#pragma unroll
    for (int i = 0; i < D; i++) md[i] = fmaf(-2.0f * dot3, vs[i], xs[i]);
    float dot4 = 0.0f;
#pragma unroll
    for (int i = 0; i < D; i++) dot4 = fmaf(vd[i], md[i], dot4);
#pragma unroll
    for (int i = 0; i < D; i++) md[i] = coef * fmaf(-2.0f * dot4, vd[i], md[i]);
}

// ===========================================================================
// CSR path kernels
// ===========================================================================
__global__ void csr_count_kernel(const void* __restrict__ ei,
                                 const void* __restrict__ x,
                                 int* __restrict__ wsI) {
    __shared__ int sfl[2];
    if (threadIdx.x == 0) detect_flags(x, ei, sfl);
    __syncthreads();
    int i64 = sfl[1];
    int e = blockIdx.x * blockDim.x + threadIdx.x;
    if (e >= N_EDGES) return;
    int s, d;
    load_edge(ei, e, i64, s, d);
    int r = (e & 3) * N_NODES;
    atomicAdd(&wsI[CNT4_OFF + r + s], 1);
    atomicAdd(&wsI[CNT4_OFF + r + d], 1);
}

__global__ __launch_bounds__(SCAN_B) void csr_scan1_kernel(int* __restrict__ wsI) {
    __shared__ int sm[SCAN_B];
    int t = threadIdx.x;
    int g = blockIdx.x * SCAN_B + t;
    int c = 0;
    if (g < N_NODES) {
        c = wsI[CNT4_OFF + g] + wsI[CNT4_OFF + N_NODES + g]
          + wsI[CNT4_OFF + 2 * N_NODES + g] + wsI[CNT4_OFF + 3 * N_NODES + g];
        wsI[DEG_OFF + g] = c;
    }
    sm[t] = c;
    __syncthreads();
    for (int st = SCAN_B / 2; st > 0; st >>= 1) {
        if (t < st) sm[t] += sm[t + st];
        __syncthreads();
    }
    if (t == 0) wsI[BS_OFF + blockIdx.x] = sm[0];
}

__global__ __launch_bounds__(SCAN_B) void csr_scan3_kernel(int* __restrict__ wsI) {
    __shared__ int sB[SCAN_B];
    __shared__ int sm[SCAN_B];
    int t = threadIdx.x;
    int bsv = (t < SCAN_G) ? wsI[BS_OFF + t] : 0;
    sB[t] = bsv;
    __syncthreads();
    for (int st = 1; st < SCAN_B; st <<= 1) {
        int u = (t >= st) ? sB[t - st] : 0;
        __syncthreads();
        sB[t] += u;
        __syncthreads();
    }
    int blockBase = sB[blockIdx.x] - wsI[BS_OFF + blockIdx.x];

    int g = blockIdx.x * SCAN_B + t;
    int c = (g < N_NODES) ? wsI[DEG_OFF + g] : 0;
    sm[t] = c;
    __syncthreads();
    for (int st = 1; st < SCAN_B; st <<= 1) {
        int u = (t >= st) ? sm[t - st] : 0;
        __syncthreads();
        sm[t] += u;
        __syncthreads();
    }
    int excl = sm[t] - c + blockBase;
    if (g < N_NODES) {
        wsI[OFF_OFF + g] = excl;
        wsI[CUR_OFF + g] = excl;
        if (g == N_NODES - 1) wsI[OFF_OFF + N_NODES] = excl + c;
    }
}

// ---------------------------------------------------------------------------
// Edge kernel — packed f32x2 math (v_pk_fma_f32). Layer-1 packs along k
// (weight pairs from LDS, horizontal add per j), layer-2 packs along i
// (accumulator pairs, one hs/hd splat per j). Same live set as the scalar
// version (~90 floats viewed as pairs), ~1.7x fewer VALU instructions.
// ---------------------------------------------------------------------------
__global__ __launch_bounds__(256) void csr_edge_kernel(
    const void* __restrict__ x,
    const void* __restrict__ ei,
    const void* __restrict__ W1,
    const void* __restrict__ b1,
    const void* __restrict__ W2,
    const void* __restrict__ b2,
    int* __restrict__ wsI)
{
    __shared__ __align__(16) float sW1[HID * 2 * D];
    __shared__ __align__(16) float sW2t[HID * D];
    __shared__ float sb1[HID];
    __shared__ float sb2[D];
    __shared__ int sfl[2];

    if (threadIdx.x == 0) detect_flags(x, ei, sfl);
    __syncthreads();
    int f32 = sfl[0], i64 = sfl[1];
    stage_weights(W1, b1, W2, b2, f32, sW1, sW2t, sb1, sb2);
    __syncthreads();

    int e = blockIdx.x * 256 + threadIdx.x;
    if (e >= N_EDGES) return;

    int s, d;
    load_edge(ei, e, i64, s, d);

    f32x2 xs2[8], xd2[8];
    load16_p(x, (long long)s * D, f32, xs2);
    load16_p(x, (long long)d * D, f32, xd2);

    float degs = (float)wsI[DEG_OFF + s];
    float degd = (float)wsI[DEG_OFF + d];
    float coef = (1.0f / sqrtf(fmaxf(degs, 1e-5f))) * (1.0f / sqrtf(fmaxf(degd, 1e-5f)));

    f32x2 vs2[8], vd2[8];
    const f32x2* sb2v = (const f32x2*)sb2;
#pragma unroll
    for (int i = 0; i < 8; i++) { vs2[i] = sb2v[i]; vd2[i] = sb2v[i]; }

#pragma unroll 4
    for (int j = 0; j < HID; j++) {
        const f32x2* w = (const f32x2*)&sW1[j * 2 * D];   // 16 pairs
        f32x2 hsv = {0.0f, 0.0f}, hdv = {0.0f, 0.0f};
#pragma unroll
        for (int t = 0; t < 8; t++) {
            f32x2 wv = w[t];
            hsv = pk_fma(wv, xs2[t], hsv);
            hdv = pk_fma(wv, xd2[t], hdv);
        }
#pragma unroll
        for (int t = 0; t < 8; t++) {
            f32x2 wv = w[8 + t];
            hsv = pk_fma(wv, xd2[t], hsv);
            hdv = pk_fma(wv, xs2[t], hdv);
        }
        float bj = sb1[j];
        float hs = fmaxf(hsv.x + hsv.y + bj, 0.0f);
        float hd = fmaxf(hdv.x + hdv.y + bj, 0.0f);
        f32x2 hsp = {hs, hs}, hdp = {hd, hd};
        const f32x2* w2 = (const f32x2*)&sW2t[j * D];      // 8 pairs
#pragma unroll
        for (int t = 0; t < 8; t++) {
            f32x2 u = w2[t];
            vs2[t] = pk_fma(u, hsp, vs2[t]);
            vd2[t] = pk_fma(u, hdp, vd2[t]);
        }
    }

    // normalize (packed accumulate + horizontal)
    f32x2 nsa = {0.0f, 0.0f}, nda = {0.0f, 0.0f};
#pragma unroll
    for (int t = 0; t < 8; t++) {
        nsa = pk_fma(vs2[t], vs2[t], nsa);
        nda = pk_fma(vd2[t], vd2[t], nda);
    }
    float is_ = 1.0f / fmaxf(sqrtf(nsa.x + nsa.y), 1e-12f);
    float id_ = 1.0f / fmaxf(sqrtf(nda.x + nda.y), 1e-12f);
    f32x2 isp = {is_, is_}, idp = {id_, id_};
#pragma unroll
    for (int t = 0; t < 8; t++) { vs2[t] *= isp; vd2[t] *= idp; }

    float* msg = (float*)(wsI + MSG_OFF_I);

    // ms = coef * Hs(Hd(xd))
    {
        f32x2 d1a = {0.0f, 0.0f};
#pragma unroll
        for (int t = 0; t < 8; t++) d1a = pk_fma(vd2[t], xd2[t], d1a);
        float dot1 = d1a.x + d1a.y;
        f32x2 c1 = {-2.0f * dot1, -2.0f * dot1};
        f32x2 ms2[8];
#pragma unroll
        for (int t = 0; t < 8; t++) ms2[t] = pk_fma(c1, vd2[t], xd2[t]);
        f32x2 d2a = {0.0f, 0.0f};
#pragma unroll
        for (int t = 0; t < 8; t++) d2a = pk_fma(vs2[t], ms2[t], d2a);
        float dot2 = d2a.x + d2a.y;
        f32x2 c2 = {-2.0f * dot2, -2.0f * dot2};
        f32x2 cf = {coef, coef};
#pragma unroll
        for (int t = 0; t < 8; t++) ms2[t] = pk_fma(c2, vs2[t], ms2[t]) * cf;
        int slot_s = atomicAdd(&wsI[CUR_OFF + s], 1);
        float4* m0 = (float4*)(msg + (long long)slot_s * D);
#pragma unroll
        for (int t = 0; t < 4; t++)
            m0[t] = make_float4(ms2[2 * t].x, ms2[2 * t].y, ms2[2 * t + 1].x, ms2[2 * t + 1].y);
    }

    // md = coef * Hd(Hs(xs))
    {
        f32x2 d3a = {0.0f, 0.0f};
#pragma unroll
        for (int t = 0; t < 8; t++) d3a = pk_fma(vs2[t], xs2[t], d3a);
        float dot3 = d3a.x + d3a.y;
        f32x2 c3 = {-2.0f * dot3, -2.0f * dot3};
        f32x2 md2[8];
#pragma unroll
        for (int t = 0; t < 8; t++) md2[t] = pk_fma(c3, vs2[t], xs2[t]);
        f32x2 d4a = {0.0f, 0.0f};
#pragma unroll
        for (int t = 0; t < 8; t++) d4a = pk_fma(vd2[t], md2[t], d4a);
        float dot4 = d4a.x + d4a.y;
        f32x2 c4 = {-2.0f * dot4, -2.0f * dot4};
        f32x2 cf = {coef, coef};
#pragma unroll
        for (int t = 0; t < 8; t++) md2[t] = pk_fma(c4, vd2[t], md2[t]) * cf;
        int slot_d = atomicAdd(&wsI[CUR_OFF + d], 1);
        float4* m1 = (float4*)(msg + (long long)slot_d * D);
#pragma unroll
        for (int t = 0; t < 4; t++)
            m1[t] = make_float4(md2[2 * t].x, md2[2 * t].y, md2[2 * t + 1].x, md2[2 * t + 1].y);
    }
}

// Gather: 4 lanes per node (lane c -> dims 4c..4c+3), unroll-2 accumulation.
__global__ __launch_bounds__(256) void csr_gather_kernel(
    const void* __restrict__ x,
    const void* __restrict__ ei,
    const int* __restrict__ wsI,
    void* __restrict__ out)
{
    __shared__ int sfl[2];
    if (threadIdx.x == 0) detect_flags(x, ei, sfl);
    __syncthreads();
    int f32 = sfl[0];

    int n = blockIdx.x * 64 + (threadIdx.x >> 2);
    int c = threadIdx.x & 3;
    if (n >= N_NODES) return;

    const int* off = wsI + OFF_OFF;
    const float4* msg4 = (const float4*)(wsI + MSG_OFF_I);

    int beg = off[n], end = off[n + 1];
    float4 a = make_float4(0.0f, 0.0f, 0.0f, 0.0f);
    int it = beg;
    for (; it + 2 <= end; it += 2) {
        float4 u = msg4[(long long)it * 4 + c];
        float4 v = msg4[(long long)(it + 1) * 4 + c];
        a.x += u.x + v.x; a.y += u.y + v.y; a.z += u.z + v.z; a.w += u.w + v.w;
    }
    if (it < end) {
        float4 u = msg4[(long long)it * 4 + c];
        a.x += u.x; a.y += u.y; a.z += u.z; a.w += u.w;
    }

    long long xb = (long long)n * D + 4 * c;
    float4 xv;
    if (f32) {
        xv = *(const float4*)((const float*)x + xb);
    } else {
        uint2 u = *(const uint2*)((const ushort_t*)x + xb);
        xv.x = lo_bf(u.x); xv.y = hi_bf(u.x);
        xv.z = lo_bf(u.y); xv.w = hi_bf(u.y);
    }
    float4 r;
    r.x = fmaxf(xv.x + a.x, 0.0f);
    r.y = fmaxf(xv.y + a.y, 0.0f);
    r.z = fmaxf(xv.z + a.z, 0.0f);
    r.w = fmaxf(xv.w + a.w, 0.0f);
    if (f32) {
        *(float4*)((float*)out + xb) = r;
    } else {
        uint2 o;
        o.x = (unsigned)f2bf(r.x) | ((unsigned)f2bf(r.y) << 16);
        o.y = (unsigned)f2bf(r.z) | ((unsigned)f2bf(r.w) << 16);
        *(uint2*)((ushort_t*)out + xb) = o;
    }
}

// ===========================================================================
// Fallback path (known-good): float atomics into acc
// ===========================================================================
__global__ void fb_init_kernel(float* __restrict__ ws,
                               const void* __restrict__ x,
                               const void* __restrict__ ei) {
    int i = blockIdx.x * blockDim.x + threadIdx.x;
    if (i < FB_FLAGS) ws[i] = 0.0f;
    if (blockIdx.x == 0 && threadIdx.x == 0)
        detect_flags(x, ei, (int*)(ws + FB_FLAGS));
}

__global__ void fb_deg_kernel(const void* __restrict__ ei, float* __restrict__ ws) {
    int i64 = ((const int*)(ws + FB_FLAGS))[1];
    int e = blockIdx.x * blockDim.x + threadIdx.x;
    if (e >= N_EDGES) return;
    int s, d;
    load_edge(ei, e, i64, s, d);
    atomicAdd(&ws[s], 1.0f);
    atomicAdd(&ws[d], 1.0f);
}

__global__ __launch_bounds__(256) void fb_edge_kernel(
    const void* __restrict__ x, const void* __restrict__ ei,
    const void* __restrict__ W1, const void* __restrict__ b1,
    const void* __restrict__ W2, const void* __restrict__ b2,
    float* __restrict__ ws)
{
    __shared__ __align__(16) float sW1[HID * 2 * D];
    __shared__ __align__(16) float sW2t[HID * D];
    __shared__ float sb1[HID];
    __shared__ float sb2[D];
    const int* flags = (const int*)(ws + FB_FLAGS);
    int f32 = flags[0], i64 = flags[1];
    stage_weights(W1, b1, W2, b2, f32, sW1, sW2t, sb1, sb2);
    __syncthreads();
    int e = blockIdx.x * blockDim.x + threadIdx.x;
    if (e >= N_EDGES) return;
    int s, d;
    load_edge(ei, e, i64, s, d);
    float xs[D], xd[D];
    load16(x, (long long)s * D, f32, xs);
    load16(x, (long long)d * D, f32, xd);
    float coef = (1.0f / sqrtf(fmaxf(ws[s], 1e-5f))) * (1.0f / sqrtf(fmaxf(ws[d], 1e-5f)));
    float ms[D], md[D];
    edge_math_v4(sW1, sW2t, sb1, sb2, xs, xd, coef, ms, md);
    float* acc = ws + FB_NDEG;
#pragma unroll
    for (int i = 0; i < D; i++) atomicAdd(&acc[(long long)s * D + i], ms[i]);
#pragma unroll
    for (int i = 0; i < D; i++) atomicAdd(&acc[(long long)d * D + i], md[i]);
}

__global__ void fb_finalize_kernel(const void* __restrict__ x,
                                   const float* __restrict__ ws,
                                   void* __restrict__ out)
{
    int f32 = ((const int*)(ws + FB_FLAGS))[0];
    const float* acc = ws + FB_NDEG;
    int i = blockIdx.x * blockDim.x + threadIdx.x;
    if (i >= FB_NACC) return;
    float v = ld_f(x, i, f32) + acc[i];
    v = fmaxf(v, 0.0f);
    if (f32) ((float*)out)[i] = v;
    else     ((__hip_bfloat16*)out)[i] = __float2bfloat16(v);
}

// ===========================================================================
extern "C" void kernel_launch(void* const* d_in, const int* in_sizes, int n_in,
                              void* d_out, int out_size, void* d_ws, size_t ws_size,
                              hipStream_t stream)
{
    const void* x  = d_in[0];
    const void* ei = d_in[1];
    const void* W1 = d_in[2];
    const void* b1 = d_in[3];
    const void* W2 = d_in[4];
    const void* b2 = d_in[5];

    int blk = 256;
    if (ws_size >= CSR_NEEDED_BYTES) {
        int* wsI = (int*)d_ws;
        hipMemsetAsync(d_ws, 0, (size_t)4 * N_NODES * sizeof(int), stream);
        csr_count_kernel<<<(N_EDGES + blk - 1) / blk, blk, 0, stream>>>(ei, x, wsI);
        csr_scan1_kernel<<<SCAN_G, SCAN_B, 0, stream>>>(wsI);
        csr_scan3_kernel<<<SCAN_G, SCAN_B, 0, stream>>>(wsI);
        csr_edge_kernel<<<(N_EDGES + blk - 1) / blk, blk, 0, stream>>>(x, ei, W1, b1, W2, b2, wsI);
        csr_gather_kernel<<<(N_NODES + 63) / 64, blk, 0, stream>>>(x, ei, wsI, d_out);
    } else {
        float* ws = (float*)d_ws;
        fb_init_kernel<<<(FB_FLAGS + blk - 1) / blk, blk, 0, stream>>>(ws, x, ei);
        fb_deg_kernel<<<(N_EDGES + blk - 1) / blk, blk, 0, stream>>>(ei, ws);
        fb_edge_kernel<<<(N_EDGES + blk - 1) / blk, blk, 0, stream>>>(x, ei, W1, b1, W2, b2, ws);
        fb_finalize_kernel<<<(FB_NACC + blk - 1) / blk, blk, 0, stream>>>(x, ws, d_out);
    }
}

// Round 12
// 200.489 us; speedup vs baseline: 1.1789x; 1.0288x over previous
//
#include <hip/hip_runtime.h>
#include <hip/hip_bf16.h>
#include <hip/hip_fp16.h>

#define N_NODES 50000
#define N_EDGES 400000
#define D 16
#define HID 64

#define SCAN_B 256
#define SCAN_G ((N_NODES + SCAN_B - 1) / SCAN_B)   // 196

typedef unsigned short ushort_t;
typedef _Float16 h16x2 __attribute__((ext_vector_type(2)));

// ---------------- int-indexed workspace layout (CSR path) ----------------
#define CNT4_OFF  0                       // [4][N] replicated counts (memset to 0)
#define DEG_OFF   (4 * N_NODES)           // [N] total degree
#define OFF_OFF   (5 * N_NODES)           // [N+1] CSR offsets
#define CUR_OFF   (6 * N_NODES + 1)       // [N] claim cursors
#define BS_OFF    (7 * N_NODES + 1)       // [SCAN_G] block sums
#define MSG_OFF_I (((BS_OFF + SCAN_G) + 3) & ~3)  // [2E*16] fp32 msgs
#define CSR_NEEDED_BYTES ((size_t)(MSG_OFF_I + 2 * N_EDGES * D) * 4 + 64)

// ---------------- fallback (atomic) layout ----------------
#define FB_NDEG   (N_NODES)
#define FB_NACC   (N_NODES * D)
#define FB_FLAGS  (FB_NDEG + FB_NACC)

// ---------------------------------------------------------------------------
// dtype helpers
// ---------------------------------------------------------------------------
__device__ __forceinline__ float bf_bits(ushort_t us) {
    return __uint_as_float(((unsigned)us) << 16);
}
__device__ __forceinline__ float lo_bf(unsigned u) { return __uint_as_float(u << 16); }
__device__ __forceinline__ float hi_bf(unsigned u) { return __uint_as_float(u & 0xffff0000u); }
__device__ __forceinline__ ushort_t f2bf(float v) {
    unsigned u = __float_as_uint(v);
    unsigned r = (u + 0x7fffu + ((u >> 16) & 1u)) >> 16;
    return (ushort_t)r;
}
__device__ __forceinline__ float ld_f(const void* p, int idx, int f32) {
    return f32 ? ((const float*)p)[idx]
               : bf_bits(((const ushort_t*)p)[idx]);
}

// pack two f32 into one f16x2 dword
__device__ __forceinline__ unsigned pack_h2(float a, float b) {
#if __has_builtin(__builtin_amdgcn_cvt_pkrtz)
    return __builtin_bit_cast(unsigned, __builtin_amdgcn_cvt_pkrtz(a, b));
#else
    h16x2 h;
    h.x = (_Float16)a;
    h.y = (_Float16)b;
    return __builtin_bit_cast(unsigned, h);
#endif
}

// f16x2 dot with f32 accumulate: v_dot2_f32_f16 (2 MACs/instr)
#if __has_builtin(__builtin_amdgcn_fdot2)
__device__ __forceinline__ float fdot2u(unsigned a, unsigned b, float c) {
    return __builtin_amdgcn_fdot2(__builtin_bit_cast(h16x2, a),
                                  __builtin_bit_cast(h16x2, b), c, false);
}
#else
__device__ __forceinline__ float fdot2u(unsigned a, unsigned b, float c) {
    h16x2 ha = __builtin_bit_cast(h16x2, a);
    h16x2 hb = __builtin_bit_cast(h16x2, b);
    return fmaf((float)ha.x, (float)hb.x, fmaf((float)ha.y, (float)hb.y, c));
}
#endif

__device__ __forceinline__ void ld16u(const unsigned* __restrict__ p, unsigned* o) {
    const uint4* q = (const uint4*)p;
    uint4 a = q[0], b = q[1], c = q[2], d = q[3];
    o[0]=a.x; o[1]=a.y; o[2]=a.z; o[3]=a.w;
    o[4]=b.x; o[5]=b.y; o[6]=b.z; o[7]=b.w;
    o[8]=c.x; o[9]=c.y; o[10]=c.z; o[11]=c.w;
    o[12]=d.x; o[13]=d.y; o[14]=d.z; o[15]=d.w;
}

__device__ __forceinline__ void load16(const void* __restrict__ p, long long base,
                                       int f32, float* o) {
    if (f32) {
        const float4* q = (const float4*)((const float*)p + base);
        float4 a = q[0], b = q[1], c = q[2], d = q[3];
        o[0]=a.x; o[1]=a.y; o[2]=a.z; o[3]=a.w;
        o[4]=b.x; o[5]=b.y; o[6]=b.z; o[7]=b.w;
        o[8]=c.x; o[9]=c.y; o[10]=c.z; o[11]=c.w;
        o[12]=d.x; o[13]=d.y; o[14]=d.z; o[15]=d.w;
    } else {
        const uint4* q = (const uint4*)((const ushort_t*)p + base);
        uint4 a = q[0], b = q[1];
        unsigned u[8] = {a.x, a.y, a.z, a.w, b.x, b.y, b.z, b.w};
#pragma unroll
        for (int k = 0; k < 8; k++) {
            o[2 * k]     = lo_bf(u[k]);
            o[2 * k + 1] = hi_bf(u[k]);
        }
    }
}

__device__ __forceinline__ void load_edge(const void* __restrict__ ei, int e, int is64,
                                          int& s, int& d) {
    if (is64) {
        const long long* p = (const long long*)ei;
        s = (int)p[e];
        d = (int)p[N_EDGES + e];
    } else {
        const int* p = (const int*)ei;
        s = p[e];
        d = p[N_EDGES + e];
    }
}

__device__ __forceinline__ void detect_flags(const void* x, const void* ei, int* flags) {
    const ushort_t* h = (const ushort_t*)x;
    int f32 = 0;
    for (int k = 0; k < 256; k++) {
        float v = bf_bits(h[k]);
        if (!(v == v) || fabsf(v) > 1.0e6f) { f32 = 1; break; }
    }
    const long long* p = (const long long*)ei;
    int i64 = 1;
    for (int k = 0; k < 16; k++) {
        long long v = p[k];
        if (v < 0 || v >= N_NODES) { i64 = 0; break; }
    }
    flags[0] = f32;
    flags[1] = i64;
}

__device__ __forceinline__ void stage_weights(
    const void* W1, const void* b1, const void* W2, const void* b2, int f32,
    float* sW1, float* sW2t, float* sb1, float* sb2)
{
    int t = threadIdx.x;
    for (int idx = t; idx < HID * 2 * D; idx += blockDim.x)
        sW1[idx] = ld_f(W1, idx, f32);
    for (int idx = t; idx < HID * D; idx += blockDim.x) {
        int j = idx / D, i = idx % D;
        sW2t[idx] = ld_f(W2, i * HID + j, f32);
    }
    if (t < HID) sb1[t] = ld_f(b1, t, f32);
    if (t < D)  sb2[t] = ld_f(b2, t, f32);
}

// ---------------------------------------------------------------------------
// Full-MLP per-edge math, f32 (safety + fallback paths)
// ---------------------------------------------------------------------------
__device__ __forceinline__ void edge_math_v4(
    const float* __restrict__ sW1, const float* __restrict__ sW2t,
    const float* __restrict__ sb1, const float* __restrict__ sb2,
    const float* xs, const float* xd, float coef,
    float* ms, float* md)
{
    float vs[D], vd[D];
#pragma unroll
    for (int i = 0; i < D; i++) { vs[i] = sb2[i]; vd[i] = sb2[i]; }
#pragma unroll 4
    for (int j = 0; j < HID; j++) {
        float hs = sb1[j], hd = sb1[j];
        const float4* w4 = (const float4*)&sW1[j * 2 * D];
#pragma unroll
        for (int t = 0; t < 4; t++) {
            float4 wv = w4[t];
            int k = 4 * t;
            hs = fmaf(wv.x, xs[k],     hs); hd = fmaf(wv.x, xd[k],     hd);
            hs = fmaf(wv.y, xs[k + 1], hs); hd = fmaf(wv.y, xd[k + 1], hd);
            hs = fmaf(wv.z, xs[k + 2], hs); hd = fmaf(wv.z, xd[k + 2], hd);
            hs = fmaf(wv.w, xs[k + 3], hs); hd = fmaf(wv.w, xd[k + 3], hd);
        }
#pragma unroll
        for (int t = 0; t < 4; t++) {
            float4 wv = w4[4 + t];
            int k = 4 * t;
            hs = fmaf(wv.x, xd[k],     hs); hd = fmaf(wv.x, xs[k],     hd);
            hs = fmaf(wv.y, xd[k + 1], hs); hd = fmaf(wv.y, xs[k + 1], hd);
            hs = fmaf(wv.z, xd[k + 2], hs); hd = fmaf(wv.z, xs[k + 2], hd);
            hs = fmaf(wv.w, xd[k + 3], hs); hd = fmaf(wv.w, xs[k + 3], hd);
        }
        hs = fmaxf(hs, 0.0f);
        hd = fmaxf(hd, 0.0f);
        const float4* w24 = (const float4*)&sW2t[j * D];
#pragma unroll
        for (int t = 0; t < 4; t++) {
            float4 u = w24[t];
            int i = 4 * t;
            vs[i]     = fmaf(u.x, hs, vs[i]);     vd[i]     = fmaf(u.x, hd, vd[i]);
            vs[i + 1] = fmaf(u.y, hs, vs[i + 1]); vd[i + 1] = fmaf(u.y, hd, vd[i + 1]);
            vs[i + 2] = fmaf(u.z, hs, vs[i + 2]); vd[i + 2] = fmaf(u.z, hd, vd[i + 2]);
            vs[i + 3] = fmaf(u.w, hs, vs[i + 3]); vd[i + 3] = fmaf(u.w, hd, vd[i + 3]);
        }
    }
    float ns = 0.0f, nd = 0.0f;
#pragma unroll
    for (int i = 0; i < D; i++) { ns = fmaf(vs[i], vs[i], ns); nd = fmaf(vd[i], vd[i], nd); }
    float is_ = 1.0f / fmaxf(sqrtf(ns), 1e-12f);
    float id_ = 1.0f / fmaxf(sqrtf(nd), 1e-12f);
#pragma unroll
    for (int i = 0; i < D; i++) { vs[i] *= is_; vd[i] *= id_; }
    float dot1 = 0.0f;
#pragma unroll
    for (int i = 0; i < D; i++) dot1 = fmaf(vd[i], xd[i], dot1);
#pragma unroll
    for (int i = 0; i < D; i++) ms[i] = fmaf(-2.0f * dot1, vd[i], xd[i]);
    float dot2 = 0.0f;
#pragma unroll
    for (int i = 0; i < D; i++) dot2 = fmaf(vs[i], ms[i], dot2);
#pragma unroll
    for (int i = 0; i < D; i++) ms[i] = coef * fmaf(-2.0f * dot2, vs[i], ms[i]);
    float dot3 = 0.0f;
#pragma unroll
    for (int i = 0; i < D; i++) dot3 = fmaf(vs[i], xs[i], dot3);
#pragma unroll
    for (int i = 0; i < D; i++) md[i] = fmaf(-2.0f * dot3, vs[i], xs[i]);
    float dot4 = 0.0f;
#pragma unroll
    for (int i = 0; i < D; i++) dot4 = fmaf(vd[i], md[i], dot4);
#pragma unroll
    for (int i = 0; i < D; i++) md[i] = coef * fmaf(-2.0f * dot4, vd[i], md[i]);
}

// ===========================================================================
// CSR path kernels
// ===========================================================================
__global__ void csr_count_kernel(const void* __restrict__ ei,
                                 const void* __restrict__ x,
                                 int* __restrict__ wsI) {
    __shared__ int sfl[2];
    if (threadIdx.x == 0) detect_flags(x, ei, sfl);
    __syncthreads();
    int i64 = sfl[1];
    int e = blockIdx.x * blockDim.x + threadIdx.x;
    if (e >= N_EDGES) return;
    int s, d;
    load_edge(ei, e, i64, s, d);
    int r = (e & 3) * N_NODES;
    atomicAdd(&wsI[CNT4_OFF + r + s], 1);
    atomicAdd(&wsI[CNT4_OFF + r + d], 1);
}

__global__ __launch_bounds__(SCAN_B) void csr_scan1_kernel(int* __restrict__ wsI) {
    __shared__ int sm[SCAN_B];
    int t = threadIdx.x;
    int g = blockIdx.x * SCAN_B + t;
    int c = 0;
    if (g < N_NODES) {
        c = wsI[CNT4_OFF + g] + wsI[CNT4_OFF + N_NODES + g]
          + wsI[CNT4_OFF + 2 * N_NODES + g] + wsI[CNT4_OFF + 3 * N_NODES + g];
        wsI[DEG_OFF + g] = c;
    }
    sm[t] = c;
    __syncthreads();
    for (int st = SCAN_B / 2; st > 0; st >>= 1) {
        if (t < st) sm[t] += sm[t + st];
        __syncthreads();
    }
    if (t == 0) wsI[BS_OFF + blockIdx.x] = sm[0];
}

__global__ __launch_bounds__(SCAN_B) void csr_scan3_kernel(int* __restrict__ wsI) {
    __shared__ int sB[SCAN_B];
    __shared__ int sm[SCAN_B];
    int t = threadIdx.x;
    int bsv = (t < SCAN_G) ? wsI[BS_OFF + t] : 0;
    sB[t] = bsv;
    __syncthreads();
    for (int st = 1; st < SCAN_B; st <<= 1) {
        int u = (t >= st) ? sB[t - st] : 0;
        __syncthreads();
        sB[t] += u;
        __syncthreads();
    }
    int blockBase = sB[blockIdx.x] - wsI[BS_OFF + blockIdx.x];

    int g = blockIdx.x * SCAN_B + t;
    int c = (g < N_NODES) ? wsI[DEG_OFF + g] : 0;
    sm[t] = c;
    __syncthreads();
    for (int st = 1; st < SCAN_B; st <<= 1) {
        int u = (t >= st) ? sm[t - st] : 0;
        __syncthreads();
        sm[t] += u;
        __syncthreads();
    }
    int excl = sm[t] - c + blockBase;
    if (g < N_NODES) {
        wsI[OFF_OFF + g] = excl;
        wsI[CUR_OFF + g] = excl;
        if (g == N_NODES - 1) wsI[OFF_OFF + N_NODES] = excl + c;
    }
}

// ---------------------------------------------------------------------------
// Edge kernel. bf16-input path: f16 weights in LDS (half the LDS bytes of
// f32 — this kernel is LDS-throughput-bound: R7/R11 both plateau ~92-110 µs
// at 192 B/lane/j; f16 gives 96 B/lane/j) + v_dot2_f32_f16 math (2 MACs/op,
// f32 accumulate; bf16->f16 is exact). f32-input path: full-f32 (tight
// threshold safety).
// ---------------------------------------------------------------------------
__global__ __launch_bounds__(256) void csr_edge_kernel(
    const void* __restrict__ x,
    const void* __restrict__ ei,
    const void* __restrict__ W1,
    const void* __restrict__ b1,
    const void* __restrict__ W2,
    const void* __restrict__ b2,
    int* __restrict__ wsI)
{
    __shared__ __align__(16) unsigned sW1h[HID * 16];   // [j][t] f16 pairs along k
    __shared__ __align__(16) unsigned sW2h[32 * 16];    // [jj][i] f16 pairs along j
    __shared__ float sb1[HID];
    __shared__ float sb2[D];
    __shared__ __align__(16) float sW1f[HID * 2 * D];   // f32 path
    __shared__ __align__(16) float sW2tf[HID * D];      // f32 path
    __shared__ int sfl[2];

    if (threadIdx.x == 0) detect_flags(x, ei, sfl);
    __syncthreads();
    int f32 = sfl[0], i64 = sfl[1];
    int t = threadIdx.x;

    if (!f32) {
        const ushort_t* W1b = (const ushort_t*)W1;
        for (int idx = t; idx < HID * 16; idx += 256) {
            int j = idx >> 4, tt = idx & 15;
            sW1h[idx] = pack_h2(bf_bits(W1b[j * 32 + 2 * tt]),
                                bf_bits(W1b[j * 32 + 2 * tt + 1]));
        }
        const ushort_t* W2b = (const ushort_t*)W2;
        for (int idx = t; idx < 32 * 16; idx += 256) {
            int jj = idx >> 4, i = idx & 15;
            sW2h[idx] = pack_h2(bf_bits(W2b[i * HID + 2 * jj]),
                                bf_bits(W2b[i * HID + 2 * jj + 1]));
        }
    } else {
        for (int idx = t; idx < HID * 2 * D; idx += 256)
            sW1f[idx] = ld_f(W1, idx, 1);
        for (int idx = t; idx < HID * D; idx += 256) {
            int j = idx / D, i = idx % D;
            sW2tf[idx] = ld_f(W2, i * HID + j, 1);
        }
    }
    if (t < HID) sb1[t] = ld_f(b1, t, f32);
    if (t < D)  sb2[t] = ld_f(b2, t, f32);
    __syncthreads();

    int e = blockIdx.x * 256 + t;
    if (e >= N_EDGES) return;

    int s, d;
    load_edge(ei, e, i64, s, d);
    float degs = (float)wsI[DEG_OFF + s];
    float degd = (float)wsI[DEG_OFF + d];
    float coef = (1.0f / sqrtf(fmaxf(degs, 1e-5f))) * (1.0f / sqrtf(fmaxf(degd, 1e-5f)));
    float* msg = (float*)(wsI + MSG_OFF_I);

    if (!f32) {
        // x rows as f16 pairs (bf16 -> f16 exact)
        unsigned xsh[8], xdh[8];
        {
            const uint4* q = (const uint4*)((const ushort_t*)x + (long long)s * D);
            uint4 a = q[0], b = q[1];
            unsigned u[8] = {a.x, a.y, a.z, a.w, b.x, b.y, b.z, b.w};
#pragma unroll
            for (int k = 0; k < 8; k++) xsh[k] = pack_h2(lo_bf(u[k]), hi_bf(u[k]));
        }
        {
            const uint4* q = (const uint4*)((const ushort_t*)x + (long long)d * D);
            uint4 a = q[0], b = q[1];
            unsigned u[8] = {a.x, a.y, a.z, a.w, b.x, b.y, b.z, b.w};
#pragma unroll
            for (int k = 0; k < 8; k++) xdh[k] = pack_h2(lo_bf(u[k]), hi_bf(u[k]));
        }

        float vs[D], vd[D];
#pragma unroll
        for (int i = 0; i < D; i++) { vs[i] = sb2[i]; vd[i] = sb2[i]; }

#pragma unroll 2
        for (int jj = 0; jj < 32; jj++) {
            unsigned wr[32];                     // W1 rows 2jj, 2jj+1 (contiguous)
            ld16u(&sW1h[(2 * jj) * 16], wr);
            ld16u(&sW1h[(2 * jj) * 16 + 16], wr + 16);
            unsigned w2r[16];                    // W2 pairs for this jj
            ld16u(&sW2h[jj * 16], w2r);

            float hs0 = sb1[2 * jj],     hd0 = hs0;
            float hs1 = sb1[2 * jj + 1], hd1 = hs1;
#pragma unroll
            for (int k = 0; k < 8; k++) {        // k-pairs 0..7: [xs | .] part
                hs0 = fdot2u(wr[k],      xsh[k], hs0);
                hd0 = fdot2u(wr[k],      xdh[k], hd0);
                hs1 = fdot2u(wr[16 + k], xsh[k], hs1);
                hd1 = fdot2u(wr[16 + k], xdh[k], hd1);
            }
#pragma unroll
            for (int k = 0; k < 8; k++) {        // k-pairs 8..15: [. | xd] part
                hs0 = fdot2u(wr[8 + k],  xdh[k], hs0);
                hd0 = fdot2u(wr[8 + k],  xsh[k], hd0);
                hs1 = fdot2u(wr[24 + k], xdh[k], hs1);
                hd1 = fdot2u(wr[24 + k], xsh[k], hd1);
            }
            hs0 = fmaxf(hs0, 0.0f); hd0 = fmaxf(hd0, 0.0f);
            hs1 = fmaxf(hs1, 0.0f); hd1 = fmaxf(hd1, 0.0f);
            unsigned hsp = pack_h2(hs0, hs1);
            unsigned hdp = pack_h2(hd0, hd1);
#pragma unroll
            for (int i = 0; i < D; i++) {
                vs[i] = fdot2u(w2r[i], hsp, vs[i]);
                vd[i] = fdot2u(w2r[i], hdp, vd[i]);
            }
        }

        // epilogue (f32): recover xs/xd exactly from f16 pairs
        float xs[D], xd[D];
#pragma unroll
        for (int k = 0; k < 8; k++) {
            h16x2 a = __builtin_bit_cast(h16x2, xsh[k]);
            xs[2 * k] = (float)a.x; xs[2 * k + 1] = (float)a.y;
            h16x2 b = __builtin_bit_cast(h16x2, xdh[k]);
            xd[2 * k] = (float)b.x; xd[2 * k + 1] = (float)b.y;
        }

        float ns = 0.0f, nd = 0.0f;
#pragma unroll
        for (int i = 0; i < D; i++) { ns = fmaf(vs[i], vs[i], ns); nd = fmaf(vd[i], vd[i], nd); }
        float is_ = 1.0f / fmaxf(sqrtf(ns), 1e-12f);
        float id_ = 1.0f / fmaxf(sqrtf(nd), 1e-12f);
#pragma unroll
        for (int i = 0; i < D; i++) { vs[i] *= is_; vd[i] *= id_; }

        float ms[D], md[D];
        float dot1 = 0.0f;
#pragma unroll
        for (int i = 0; i < D; i++) dot1 = fmaf(vd[i], xd[i], dot1);
#pragma unroll
        for (int i = 0; i < D; i++) ms[i] = fmaf(-2.0f * dot1, vd[i], xd[i]);
        float dot2 = 0.0f;
#pragma unroll
        for (int i = 0; i < D; i++) dot2 = fmaf(vs[i], ms[i], dot2);
#pragma unroll
        for (int i = 0; i < D; i++) ms[i] = coef * fmaf(-2.0f * dot2, vs[i], ms[i]);
        float dot3 = 0.0f;
#pragma unroll
        for (int i = 0; i < D; i++) dot3 = fmaf(vs[i], xs[i], dot3);
#pragma unroll
        for (int i = 0; i < D; i++) md[i] = fmaf(-2.0f * dot3, vs[i], xs[i]);
        float dot4 = 0.0f;
#pragma unroll
        for (int i = 0; i < D; i++) dot4 = fmaf(vd[i], md[i], dot4);
#pragma unroll
        for (int i = 0; i < D; i++) md[i] = coef * fmaf(-2.0f * dot4, vd[i], md[i]);

        int slot_s = atomicAdd(&wsI[CUR_OFF + s], 1);
        float4* m0 = (float4*)(msg + (long long)slot_s * D);
        m0[0] = make_float4(ms[0], ms[1], ms[2], ms[3]);
        m0[1] = make_float4(ms[4], ms[5], ms[6], ms[7]);
        m0[2] = make_float4(ms[8], ms[9], ms[10], ms[11]);
        m0[3] = make_float4(ms[12], ms[13], ms[14], ms[15]);
        int slot_d = atomicAdd(&wsI[CUR_OFF + d], 1);
        float4* m1 = (float4*)(msg + (long long)slot_d * D);
        m1[0] = make_float4(md[0], md[1], md[2], md[3]);
        m1[1] = make_float4(md[4], md[5], md[6], md[7]);
        m1[2] = make_float4(md[8], md[9], md[10], md[11]);
        m1[3] = make_float4(md[12], md[13], md[14], md[15]);
    } else {
        float xs[D], xd[D];
        load16(x, (long long)s * D, 1, xs);
        load16(x, (long long)d * D, 1, xd);
        float ms[D], md[D];
        edge_math_v4(sW1f, sW2tf, sb1, sb2, xs, xd, coef, ms, md);
        int slot_s = atomicAdd(&wsI[CUR_OFF + s], 1);
        float4* m0 = (float4*)(msg + (long long)slot_s * D);
        m0[0] = make_float4(ms[0], ms[1], ms[2], ms[3]);
        m0[1] = make_float4(ms[4], ms[5], ms[6], ms[7]);
        m0[2] = make_float4(ms[8], ms[9], ms[10], ms[11]);
        m0[3] = make_float4(ms[12], ms[13], ms[14], ms[15]);
        int slot_d = atomicAdd(&wsI[CUR_OFF + d], 1);
        float4* m1 = (float4*)(msg + (long long)slot_d * D);
        m1[0] = make_float4(md[0], md[1], md[2], md[3]);
        m1[1] = make_float4(md[4], md[5], md[6], md[7]);
        m1[2] = make_float4(md[8], md[9], md[10], md[11]);
        m1[3] = make_float4(md[12], md[13], md[14], md[15]);
    }
}

// Gather: 4 lanes per node (lane c -> dims 4c..4c+3), unroll-2 accumulation.
__global__ __launch_bounds__(256) void csr_gather_kernel(
    const void* __restrict__ x,
    const void* __restrict__ ei,
    const int* __restrict__ wsI,
    void* __restrict__ out)
{
    __shared__ int sfl[2];
    if (threadIdx.x == 0) detect_flags(x, ei, sfl);
    __syncthreads();
    int f32 = sfl[0];

    int n = blockIdx.x * 64 + (threadIdx.x >> 2);
    int c = threadIdx.x & 3;
    if (n >= N_NODES) return;

    const int* off = wsI + OFF_OFF;
    const float4* msg4 = (const float4*)(wsI + MSG_OFF_I);

    int beg = off[n], end = off[n + 1];
    float4 a = make_float4(0.0f, 0.0f, 0.0f, 0.0f);
    int it = beg;
    for (; it + 2 <= end; it += 2) {
        float4 u = msg4[(long long)it * 4 + c];
        float4 v = msg4[(long long)(it + 1) * 4 + c];
        a.x += u.x + v.x; a.y += u.y + v.y; a.z += u.z + v.z; a.w += u.w + v.w;
    }
    if (it < end) {
        float4 u = msg4[(long long)it * 4 + c];
        a.x += u.x; a.y += u.y; a.z += u.z; a.w += u.w;
    }

    long long xb = (long long)n * D + 4 * c;
    float4 xv;
    if (f32) {
        xv = *(const float4*)((const float*)x + xb);
    } else {
        uint2 u = *(const uint2*)((const ushort_t*)x + xb);
        xv.x = lo_bf(u.x); xv.y = hi_bf(u.x);
        xv.z = lo_bf(u.y); xv.w = hi_bf(u.y);
    }
    float4 r;
    r.x = fmaxf(xv.x + a.x, 0.0f);
    r.y = fmaxf(xv.y + a.y, 0.0f);
    r.z = fmaxf(xv.z + a.z, 0.0f);
    r.w = fmaxf(xv.w + a.w, 0.0f);
    if (f32) {
        *(float4*)((float*)out + xb) = r;
    } else {
        uint2 o;
        o.x = (unsigned)f2bf(r.x) | ((unsigned)f2bf(r.y) << 16);
        o.y = (unsigned)f2bf(r.z) | ((unsigned)f2bf(r.w) << 16);
        *(uint2*)((ushort_t*)out + xb) = o;
    }
}

// ===========================================================================
// Fallback path (known-good): float atomics into acc
// ===========================================================================
__global__ void fb_init_kernel(float* __restrict__ ws,
                               const void* __restrict__ x,
                               const void* __restrict__ ei) {
    int i = blockIdx.x * blockDim.x + threadIdx.x;
    if (i < FB_FLAGS) ws[i] = 0.0f;
    if (blockIdx.x == 0 && threadIdx.x == 0)
        detect_flags(x, ei, (int*)(ws + FB_FLAGS));
}

__global__ void fb_deg_kernel(const void* __restrict__ ei, float* __restrict__ ws) {
    int i64 = ((const int*)(ws + FB_FLAGS))[1];
    int e = blockIdx.x * blockDim.x + threadIdx.x;
    if (e >= N_EDGES) return;
    int s, d;
    load_edge(ei, e, i64, s, d);
    atomicAdd(&ws[s], 1.0f);
    atomicAdd(&ws[d], 1.0f);
}

__global__ __launch_bounds__(256) void fb_edge_kernel(
    const void* __restrict__ x, const void* __restrict__ ei,
    const void* __restrict__ W1, const void* __restrict__ b1,
    const void* __restrict__ W2, const void* __restrict__ b2,
    float* __restrict__ ws)
{
    __shared__ __align__(16) float sW1[HID * 2 * D];
    __shared__ __align__(16) float sW2t[HID * D];
    __shared__ float sb1[HID];
    __shared__ float sb2[D];
    const int* flags = (const int*)(ws + FB_FLAGS);
    int f32 = flags[0], i64 = flags[1];
    stage_weights(W1, b1, W2, b2, f32, sW1, sW2t, sb1, sb2);
    __syncthreads();
    int e = blockIdx.x * blockDim.x + threadIdx.x;
    if (e >= N_EDGES) return;
    int s, d;
    load_edge(ei, e, i64, s, d);
    float xs[D], xd[D];
    load16(x, (long long)s * D, f32, xs);
    load16(x, (long long)d * D, f32, xd);
    float coef = (1.0f / sqrtf(fmaxf(ws[s], 1e-5f))) * (1.0f / sqrtf(fmaxf(ws[d], 1e-5f)));
    float ms[D], md[D];
    edge_math_v4(sW1, sW2t, sb1, sb2, xs, xd, coef, ms, md);
    float* acc = ws + FB_NDEG;
#pragma unroll
    for (int i = 0; i < D; i++) atomicAdd(&acc[(long long)s * D + i], ms[i]);
#pragma unroll
    for (int i = 0; i < D; i++) atomicAdd(&acc[(long long)d * D + i], md[i]);
}

__global__ void fb_finalize_kernel(const void* __restrict__ x,
                                   const float* __restrict__ ws,
                                   void* __restrict__ out)
{
    int f32 = ((const int*)(ws + FB_FLAGS))[0];
    const float* acc = ws + FB_NDEG;
    int i = blockIdx.x * blockDim.x + threadIdx.x;
    if (i >= FB_NACC) return;
    float v = ld_f(x, i, f32) + acc[i];
    v = fmaxf(v, 0.0f);
    if (f32) ((float*)out)[i] = v;
    else     ((__hip_bfloat16*)out)[i] = __float2bfloat16(v);
}

// ===========================================================================
extern "C" void kernel_launch(void* const* d_in, const int* in_sizes, int n_in,
                              void* d_out, int out_size, void* d_ws, size_t ws_size,
                              hipStream_t stream)
{
    const void* x  = d_in[0];
    const void* ei = d_in[1];
    const void* W1 = d_in[2];
    const void* b1 = d_in[3];
    const void* W2 = d_in[4];
    const void* b2 = d_in[5];

    int blk = 256;
    if (ws_size >= CSR_NEEDED_BYTES) {
        int* wsI = (int*)d_ws;
        hipMemsetAsync(d_ws, 0, (size_t)4 * N_NODES * sizeof(int), stream);
        csr_count_kernel<<<(N_EDGES + blk - 1) / blk, blk, 0, stream>>>(ei, x, wsI);
        csr_scan1_kernel<<<SCAN_G, SCAN_B, 0, stream>>>(wsI);
        csr_scan3_kernel<<<SCAN_G, SCAN_B, 0, stream>>>(wsI);
        csr_edge_kernel<<<(N_EDGES + blk - 1) / blk, blk, 0, stream>>>(x, ei, W1, b1, W2, b2, wsI);
        csr_gather_kernel<<<(N_NODES + 63) / 64, blk, 0, stream>>>(x, ei, wsI, d_out);
    } else {
        float* ws = (float*)d_ws;
        fb_init_kernel<<<(FB_FLAGS + blk - 1) / blk, blk, 0, stream>>>(ws, x, ei);
        fb_deg_kernel<<<(N_EDGES + blk - 1) / blk, blk, 0, stream>>>(ei, ws);
        fb_edge_kernel<<<(N_EDGES + blk - 1) / blk, blk, 0, stream>>>(x, ei, W1, b1, W2, b2, ws);
        fb_finalize_kernel<<<(FB_NACC + blk - 1) / blk, blk, 0, stream>>>(x, ws, d_out);
    }
}